// Round 3
// baseline (115.841 us; speedup 1.0000x reference)
//
#include <hip/hip_runtime.h>

// EmbeddingWithDropout: out[b,s,:] = weight[x[b,s],:] * ((u[x[b,s]] >= 0.1) ? 1/0.9 : 0)
// x: [64,2048] int32, weight: [100000,128] fp32, u: [100000] fp32
// out: [64,2048,128] fp32
//
// Memory-bound random gather + streaming write.
//  - 32 lanes per row (one float4/lane), wave covers 2 rows: fully coalesced.
//  - Each thread processes TWO distant float4s (independent x->u->weight
//    chains) for 2x memory-level parallelism per wave.
//  - Non-temporal stores (via clang native vector type — HIP_vector_type
//    structs are rejected by the builtin): keep the 64 MB streaming output
//    out of L2 so L2 caches more of the 51 MB gathered table.

#define DIM 128
#define VEC_PER_ROW (DIM / 4)   // 32 float4 per row

typedef float v4f __attribute__((ext_vector_type(4)));

__global__ __launch_bounds__(256) void embed_dropout_kernel(
    const int* __restrict__ x,
    const float* __restrict__ weight,
    const float* __restrict__ u,
    v4f* __restrict__ out,
    int n_tokens, int half_vec)   // half_vec = n_tokens*32/2
{
    int gid = blockIdx.x * blockDim.x + threadIdx.x;
    if (gid >= half_vec) return;
    int gid2 = gid + half_vec;

    // chain A
    int tokA = gid >> 5;
    int offA = gid & 31;
    // chain B (independent)
    int tokB = gid2 >> 5;
    int offB = gid2 & 31;

    int idxA = x[tokA];
    int idxB = x[tokB];

    float uA = u[idxA];
    float uB = u[idxB];
    float keepA = (uA >= 0.1f) ? (1.0f / 0.9f) : 0.0f;
    float keepB = (uB >= 0.1f) ? (1.0f / 0.9f) : 0.0f;

    const v4f* wA = reinterpret_cast<const v4f*>(weight)
                    + (size_t)idxA * VEC_PER_ROW + offA;
    const v4f* wB = reinterpret_cast<const v4f*>(weight)
                    + (size_t)idxB * VEC_PER_ROW + offB;
    v4f vA = *wA;
    v4f vB = *wB;

    vA *= keepA;
    vB *= keepB;

    __builtin_nontemporal_store(vA, out + gid);
    __builtin_nontemporal_store(vB, out + gid2);
}

extern "C" void kernel_launch(void* const* d_in, const int* in_sizes, int n_in,
                              void* d_out, int out_size, void* d_ws, size_t ws_size,
                              hipStream_t stream) {
    const int*   x      = (const int*)d_in[0];     // [64*2048]
    const float* weight = (const float*)d_in[1];   // [100000*128]
    const float* u      = (const float*)d_in[2];   // [100000]
    v4f*         out    = (v4f*)d_out;

    int n_tokens = in_sizes[0];                    // 131072
    int n_vec4   = n_tokens * VEC_PER_ROW;         // 4,194,304 float4
    int half_vec = n_vec4 / 2;                     // each thread does 2
    int block = 256;
    int grid  = (half_vec + block - 1) / block;    // 8192

    embed_dropout_kernel<<<grid, block, 0, stream>>>(x, weight, u, out,
                                                     n_tokens, half_vec);
}